// Round 21
// baseline (274.672 us; speedup 1.0000x reference)
//
#include <hip/hip_runtime.h>
#include <hip/hip_bf16.h>

typedef __hip_bfloat16 bf16;

#define NB 8
#define NS 1024
#define ND 512
#define NH 8
#define NDH 64
#define NDF 2048

typedef __attribute__((ext_vector_type(8))) short s16x8;
typedef __attribute__((ext_vector_type(4))) float f32x4;

__device__ __forceinline__ void storev(float* p, float v) { *p = v; }
__device__ __forceinline__ void storev(bf16* p, float v) { *p = __float2bfloat16(v); }
__device__ __forceinline__ short f2bf(float f) {
    bf16 h = __float2bfloat16(f);
    return *reinterpret_cast<short*>(&h);
}
__device__ __forceinline__ float bf2f(short s) {
    bf16 h = *reinterpret_cast<bf16*>(&s);
    return __bfloat162float(h);
}

// direct global->LDS 16B copy (wave-uniform LDS base + lane*16 dest)
__device__ __forceinline__ void gload_lds16(const short* g, short* l) {
    __builtin_amdgcn_global_load_lds(
        (const __attribute__((address_space(1))) unsigned int*)g,
        (__attribute__((address_space(3))) unsigned int*)l, 16, 0, 0);
}

// XCD-aware bijective block swizzle (T1): consecutive logical rows group on
// one XCD so A row-panels stay in its private L2. Requires nwg % 8 == 0.
__device__ __forceinline__ void xcd_swizzle(int& bx, int& by) {
    int gx = gridDim.x;
    int nwg = gx * gridDim.y;
    int flat = by * gx + bx;
    int swz = (flat & 7) * (nwg >> 3) + (flat >> 3);
    bx = swz % gx;
    by = swz / gx;
}

// ---------------------------------------------------------------------------
// Merged prep: z<7 -> weight transposes (W[K][N] f32 -> Wt[N][K] bf16);
// z==7 -> input casts f32->bf16 (grid-stride).
// ---------------------------------------------------------------------------
struct TP7 {
    const float* src[7];
    short* dst[7];
    int K[7];
    int N[7];
};

__global__ __launch_bounds__(256) void prep_kernel(
    TP7 p, const float4* __restrict__ inA, int n4a,
    const float4* __restrict__ inB, int n4b,
    short* __restrict__ outA, short* __restrict__ outB)
{
    __shared__ float t[32][33];
    const int z = blockIdx.z;
    if (z == 7) {
        for (int i = blockIdx.x * 256 + threadIdx.x; i < n4a + n4b; i += 1024 * 256) {
            const float4* s; short* d; int j;
            if (i < n4a) { s = inA; d = outA; j = i; }
            else { s = inB; d = outB; j = i - n4a; }
            float4 v = s[j];
            short4 o;
            o.x = f2bf(v.x); o.y = f2bf(v.y); o.z = f2bf(v.z); o.w = f2bf(v.w);
            *reinterpret_cast<short4*>(d + (size_t)j * 4) = o;
        }
        return;
    }
    const float* src = p.src[z];
    short* dst = p.dst[z];
    const int K = p.K[z], N = p.N[z];
    const int ntx = N >> 5;
    const int f = blockIdx.x;
    if (f >= ntx * (K >> 5)) return;
    const int n0 = (f % ntx) * 32, k0 = (f / ntx) * 32;
    const int tx = threadIdx.x & 31, ty = threadIdx.x >> 5;
#pragma unroll
    for (int i = 0; i < 4; ++i)
        t[ty + i * 8][tx] = src[(size_t)(k0 + ty + i * 8) * N + n0 + tx];
    __syncthreads();
#pragma unroll
    for (int i = 0; i < 4; ++i)
        dst[(size_t)(n0 + ty + i * 8) * K + k0 + tx] = f2bf(t[tx][ty + i * 8]);
}

// ---------------------------------------------------------------------------
// MFMA bf16 GEMM, 128x128 tile, BK=32 double-buffered (R15) + XCD swizzle.
// ---------------------------------------------------------------------------
template <typename CT>
__global__ __launch_bounds__(256) void mfma_gemm_kernel(
    const short* __restrict__ A, const short* __restrict__ Bt,
    const float* __restrict__ bias, CT* __restrict__ C,
    int M, int N, int K, int doRelu)
{
    __shared__ __align__(16) short As[2][128 * 32];
    __shared__ __align__(16) short Bs[2][128 * 32];
    int bx = blockIdx.x, by = blockIdx.y;
    xcd_swizzle(bx, by);
    const int row0 = by * 128;
    const int col0 = bx * 128;
    const int tid = threadIdx.x;
    const int lane = tid & 63, w = tid >> 6;
    const int wm = w >> 1, wn = w & 1;
    const int lm = lane & 15, kq = lane >> 4;
    const int srow = lane >> 2;
    const int schk = lane & 3;

    f32x4 acc[4][4] = {};

    auto stage = [&](int bufi, int k0) {
#pragma unroll
        for (int p = 0; p < 2; ++p) {
            int rbase = p * 64 + w * 16;
            int r = rbase + srow;
            int gc = schk ^ ((r >> 1) & 3);
            gload_lds16(A  + (size_t)(row0 + r) * K + k0 + gc * 8, &As[bufi][rbase * 32]);
            gload_lds16(Bt + (size_t)(col0 + r) * K + k0 + gc * 8, &Bs[bufi][rbase * 32]);
        }
    };

    stage(0, 0);
    __syncthreads();          // tile 0 resident
    int cur = 0;
    for (int k0 = 0; k0 < K; k0 += 32) {
        if (k0 + 32 < K) stage(cur ^ 1, k0 + 32);   // issue next-tile loads
        s16x8 af[4], bfr[4];
#pragma unroll
        for (int i = 0; i < 4; ++i) {
            int ra = wm * 64 + i * 16 + lm;
            int rb = wn * 64 + i * 16 + lm;
            af[i]  = *reinterpret_cast<const s16x8*>(
                &As[cur][ra * 32 + (kq ^ ((ra >> 1) & 3)) * 8]);
            bfr[i] = *reinterpret_cast<const s16x8*>(
                &Bs[cur][rb * 32 + (kq ^ ((rb >> 1) & 3)) * 8]);
        }
#pragma unroll
        for (int i = 0; i < 4; ++i)
#pragma unroll
            for (int j = 0; j < 4; ++j)
                acc[i][j] = __builtin_amdgcn_mfma_f32_16x16x32_bf16(
                    af[i], bfr[j], acc[i][j], 0, 0, 0);
        __syncthreads();      // drains vmcnt: next tile resident
        cur ^= 1;
    }

#pragma unroll
    for (int i = 0; i < 4; ++i) {
        int cr0 = row0 + wm * 64 + i * 16 + kq * 4;
#pragma unroll
        for (int j = 0; j < 4; ++j) {
            int cc = col0 + wn * 64 + j * 16 + lm;
            float bv = bias ? bias[cc] : 0.0f;
#pragma unroll
            for (int r = 0; r < 4; ++r) {
                float v = acc[i][j][r] + bv;
                if (doRelu) v = fmaxf(v, 0.0f);
                storev(&C[(size_t)(cr0 + r) * N + cc], v);
            }
        }
    }
}

// ---------------------------------------------------------------------------
// MFMA bf16 GEMM, 128x64 tile, BK=64, 2-phase double-buffer (R14) + XCD
// swizzle. R21: optional RESIDUAL fused into the epilogue (v += resid[idx])
// so the following LN reads ONE stream instead of two (-16 MB per use).
// (acc+bias)+resid is bit-identical to the old resid+(acc+bias).
// ---------------------------------------------------------------------------
template <typename CT>
__global__ __launch_bounds__(256) void mfma_gemm64_kernel(
    const short* __restrict__ A, const short* __restrict__ Bt,
    const float* __restrict__ bias, const float* __restrict__ resid,
    CT* __restrict__ C, int M, int N, int K, int doRelu)
{
    __shared__ __align__(16) short As[2][128 * 64];
    __shared__ __align__(16) short Bs[2][64 * 64];
    int bx = blockIdx.x, by = blockIdx.y;
    xcd_swizzle(bx, by);
    const int row0 = by * 128;
    const int col0 = bx * 64;
    const int tid = threadIdx.x;
    const int lane = tid & 63, w = tid >> 6;
    const int wm = w >> 1, wn = w & 1;
    const int lm = lane & 15, kq = lane >> 4;
    const int srow8 = lane >> 3;
    const int schk8 = lane & 7;

    f32x4 acc[4][2] = {};

    auto stage = [&](int bufi, int k0) {
#pragma unroll
        for (int p = 0; p < 4; ++p) {
            int rbase = p * 32 + w * 8;
            int r = rbase + srow8;
            int gc = schk8 ^ (r & 7);
            gload_lds16(A + (size_t)(row0 + r) * K + k0 + gc * 8, &As[bufi][rbase * 64]);
        }
#pragma unroll
        for (int p = 0; p < 2; ++p) {
            int rbase = p * 32 + w * 8;
            int r = rbase + srow8;
            int gc = schk8 ^ (r & 7);
            gload_lds16(Bt + (size_t)(col0 + r) * K + k0 + gc * 8, &Bs[bufi][rbase * 64]);
        }
    };

    stage(0, 0);
    __syncthreads();          // drain: tile 0 resident
    int cur = 0;
    for (int k0 = 0; k0 < K; k0 += 64) {
        if (k0 + 64 < K) stage(cur ^ 1, k0 + 64);   // issue next-tile loads
#pragma unroll
        for (int ks = 0; ks < 2; ++ks) {
            s16x8 af[4], bfr[2];
#pragma unroll
            for (int i = 0; i < 4; ++i) {
                int ra = wm * 64 + i * 16 + lm;
                af[i] = *reinterpret_cast<const s16x8*>(
                    &As[cur][ra * 64 + ((4 * ks + kq) ^ (lm & 7)) * 8]);
            }
#pragma unroll
            for (int j = 0; j < 2; ++j) {
                int rb = wn * 32 + j * 16 + lm;
                bfr[j] = *reinterpret_cast<const s16x8*>(
                    &Bs[cur][rb * 64 + ((4 * ks + kq) ^ (lm & 7)) * 8]);
            }
#pragma unroll
            for (int i = 0; i < 4; ++i)
#pragma unroll
                for (int j = 0; j < 2; ++j)
                    acc[i][j] = __builtin_amdgcn_mfma_f32_16x16x32_bf16(
                        af[i], bfr[j], acc[i][j], 0, 0, 0);
        }
        __syncthreads();      // drains vmcnt: next tile resident; cur consumed
        cur ^= 1;
    }

#pragma unroll
    for (int i = 0; i < 4; ++i) {
        int cr0 = row0 + wm * 64 + i * 16 + kq * 4;
#pragma unroll
        for (int j = 0; j < 2; ++j) {
            int cc = col0 + wn * 32 + j * 16 + lm;
            float bv = bias ? bias[cc] : 0.0f;
#pragma unroll
            for (int r = 0; r < 4; ++r) {
                float v = acc[i][j][r] + bv;
                if (resid) v += resid[(size_t)(cr0 + r) * N + cc];
                if (doRelu) v = fmaxf(v, 0.0f);
                storev(&C[(size_t)(cr0 + r) * N + cc], v);
            }
        }
    }
}

// ---------------------------------------------------------------------------
// Fused QKV + rel projection, BK=32 double-buffered (R15) + XCD swizzle.
// V epilogue (sec==2) writes DIRECTLY TRANSPOSED into vT (R18 win).
// qv not materialized (R19 win): fused_attn derives av = aq - ub + vb.
// ---------------------------------------------------------------------------
__global__ __launch_bounds__(256) void qkvr_gemm_kernel(
    const short* __restrict__ x_bf, const short* __restrict__ Wqkv,
    const short* __restrict__ rel_bf, const short* __restrict__ WrT,
    const float* __restrict__ ub,
    short* __restrict__ qu,
    short* __restrict__ kb, short* __restrict__ vT,
    short* __restrict__ r_bf)
{
    int bx = blockIdx.x, by = blockIdx.y;
    xcd_swizzle(bx, by);
    const int isRel = bx >= 12;
    if (isRel && by >= 8) return;
    const short* A  = isRel ? rel_bf : x_bf;
    const short* Bt = isRel ? WrT : Wqkv;
    const int col0 = isRel ? (bx - 12) * 128 : bx * 128;
    const int row0 = by * 128;

    __shared__ __align__(16) short As[2][128 * 32];
    __shared__ __align__(16) short Bs[2][128 * 32];
    const int tid = threadIdx.x;
    const int lane = tid & 63, w = tid >> 6;
    const int wm = w >> 1, wn = w & 1;
    const int lm = lane & 15, kq = lane >> 4;
    const int srow = lane >> 2;
    const int schk = lane & 3;

    f32x4 acc[4][4] = {};

    auto stage = [&](int bufi, int k0) {
#pragma unroll
        for (int p = 0; p < 2; ++p) {
            int rbase = p * 64 + w * 16;
            int r = rbase + srow;
            int gc = schk ^ ((r >> 1) & 3);
            gload_lds16(A  + (size_t)(row0 + r) * ND + k0 + gc * 8, &As[bufi][rbase * 32]);
            gload_lds16(Bt + (size_t)(col0 + r) * ND + k0 + gc * 8, &Bs[bufi][rbase * 32]);
        }
    };

    stage(0, 0);
    __syncthreads();
    int cur = 0;
    for (int k0 = 0; k0 < ND; k0 += 32) {
        if (k0 + 32 < ND) stage(cur ^ 1, k0 + 32);
        s16x8 af[4], bfr[4];
#pragma unroll
        for (int i = 0; i < 4; ++i) {
            int ra = wm * 64 + i * 16 + lm;
            int rb = wn * 64 + i * 16 + lm;
            af[i]  = *reinterpret_cast<const s16x8*>(
                &As[cur][ra * 32 + (kq ^ ((ra >> 1) & 3)) * 8]);
            bfr[i] = *reinterpret_cast<const s16x8*>(
                &Bs[cur][rb * 32 + (kq ^ ((rb >> 1) & 3)) * 8]);
        }
#pragma unroll
        for (int i = 0; i < 4; ++i)
#pragma unroll
            for (int j = 0; j < 4; ++j)
                acc[i][j] = __builtin_amdgcn_mfma_f32_16x16x32_bf16(
                    af[i], bfr[j], acc[i][j], 0, 0, 0);
        __syncthreads();
        cur ^= 1;
    }

    const int sec = col0 >> 9;  // uniform per block (qkv path)
#pragma unroll
    for (int i = 0; i < 4; ++i) {
        int cr0 = row0 + wm * 64 + i * 16 + kq * 4;
#pragma unroll
        for (int j = 0; j < 4; ++j) {
            int cc = col0 + wn * 64 + j * 16 + lm;
            int c5 = cc & 511;
            if (!isRel && sec == 2) {
                // V: direct transposed store (4 consecutive s at fixed h,n)
                int hh = c5 >> 6, nn = c5 & 63;
                int bb_ = row0 >> 10;                 // block spans one b
                int s = cr0 - (bb_ << 10);
                short4 o;
                o.x = f2bf(acc[i][j][0]); o.y = f2bf(acc[i][j][1]);
                o.z = f2bf(acc[i][j][2]); o.w = f2bf(acc[i][j][3]);
                *reinterpret_cast<short4*>(
                    vT + (((size_t)(bb_ * NH + hh) * NDH + nn) * NS + s)) = o;
            } else {
#pragma unroll
                for (int r = 0; r < 4; ++r) {
                    float a = acc[i][j][r];
                    size_t idx = (size_t)(cr0 + r) * ND + c5;
                    if (isRel) {
                        r_bf[idx] = f2bf(a);
                    } else if (sec == 0) {
                        qu[idx] = f2bf(a + ub[c5]);
                    } else {
                        kb[idx] = f2bf(a);
                    }
                }
            }
        }
    }
}

// ---------------------------------------------------------------------------
// Fused attention — R7 structure (frozen) + av derived in-register (R19) +
// hoisted zero-fill and full-tile fast path (R20, measured win).
// ---------------------------------------------------------------------------
__global__ __launch_bounds__(256) void fused_attn_kernel(
    const short* __restrict__ qu,
    const short* __restrict__ kb, const short* __restrict__ rb,
    const short* __restrict__ vT,
    const float* __restrict__ ub, const float* __restrict__ vb,
    float* __restrict__ attn, short* __restrict__ ctx)
{
    __shared__ __align__(16) short K_s[64 * 64];
    __shared__ __align__(16) short V_s[64 * 64];
    __shared__ __align__(16) short r_s[2][64 * 64];
    __shared__ __align__(16) short bd_s[64][80];  // bd gather tile / e overlay

    const int bid = blockIdx.x;
    const int strip = 15 - (bid >> 6);      // heavy strips first
    const int bh = bid & 63;
    const int h = bh & (NH - 1), b = bh >> 3;
    const int q0 = strip * 64;
    const int n_kt = strip + 1;
    const int tid = threadIdx.x;
    const int lane = tid & 63, w = tid >> 6;
    const int lm = lane & 15, kq = lane >> 4;
    const int woff = 48 - w * 16;           // per-wave u-window base
    const int srow8 = lane >> 3;            // staging: row within 8-row group
    const int schk8 = lane & 7;             // staging: 16B chunk within 64-short row

    // loop-invariant A-fragments; av derived from aq via bias delta
    s16x8 aq[2], av[2];
#pragma unroll
    for (int ks = 0; ks < 2; ++ks) {
        const size_t off = (size_t)(b * NS + q0 + w * 16 + lm) * ND + h * NDH + ks * 32 + kq * 8;
        aq[ks] = *reinterpret_cast<const s16x8*>(qu + off);
        const int dbase = h * NDH + ks * 32 + kq * 8;
#pragma unroll
        for (int e = 0; e < 8; ++e) {
            float t = bf2f(aq[ks][e]) - ub[dbase + e] + vb[dbase + e];
            av[ks][e] = f2bf(t);
        }
    }

    // zero-fill k >= n_kt*64 FIRST: pure stores overlap first-tile latency;
    // region disjoint from everything the passes write.
    {
        const int z = NS - n_kt * 64;
        if (z > 0) {
            const int z4 = z >> 2;
            float4 zz = make_float4(0.f, 0.f, 0.f, 0.f);
            for (int i = tid; i < 64 * z4; i += 256) {
                int zr = i / z4, zc = i - zr * z4;
                *reinterpret_cast<float4*>(
                    attn + ((size_t)bh * NS + q0 + zr) * NS + n_kt * 64 + zc * 4) = zz;
            }
        }
    }

    f32x4 apv[4] = {};
    float linv[4];

    for (int pass = 0; pass < 2; ++pass) {
        float lsum[4] = {0.f, 0.f, 0.f, 0.f};
        for (int kt = 0; kt < n_kt; ++kt) {
            const int k0 = kt * 64;
            const int ub0 = k0 - q0 + 960;   // u-window base (>= 0)
            __syncthreads();                 // prev tile fully consumed
            // K tile: 64 rows x 64 shorts, linear, swizzled source chunk
#pragma unroll
            for (int p = 0; p < 2; ++p) {
                int rbase = p * 32 + w * 8;
                int grow = rbase + srow8;
                int gc = schk8 ^ (grow & 7);
                gload_lds16(kb + (size_t)(b * NS + k0 + grow) * ND + h * NDH + gc * 8,
                            K_s + rbase * 64);
            }
            if (pass) {
#pragma unroll
                for (int p = 0; p < 2; ++p) {
                    int rbase = p * 32 + w * 8;
                    int grow = rbase + srow8;
                    int gc = schk8 ^ (grow & 7);
                    gload_lds16(vT + ((size_t)bh * NDH + grow) * NS + k0 + gc * 8,
                                V_s + rbase * 64);
                }
            }
            // r ping-pong: L_kt in r_s[kt&1], U_kt in r_s[(kt+1)&1]
            if (kt == 0) {
#pragma unroll
                for (int half = 0; half < 2; ++half)
#pragma unroll
                    for (int p = 0; p < 2; ++p) {
                        int rbase = p * 32 + w * 8;
                        int grow = rbase + srow8;
                        int ur = ub0 + half * 64 + grow; ur = ur > 1023 ? 1023 : ur;
                        int gc = schk8 ^ (grow & 7);
                        gload_lds16(rb + (size_t)ur * ND + h * NDH + gc * 8,
                                    r_s[half] + rbase * 64);
                    }
            } else {
#pragma unroll
                for (int p = 0; p < 2; ++p) {
                    int rbase = p * 32 + w * 8;
                    int grow = rbase + srow8;
                    int ur = ub0 + 64 + grow; ur = ur > 1023 ? 1023 : ur;
                    int gc = schk8 ^ (grow & 7);
                    gload_lds16(rb + (size_t)ur * ND + h * NDH + gc * 8,
                                r_s[(kt + 1) & 1] + rbase * 64);
                }
            }
            __syncthreads();

            f32x4 aac[4] = {};
            f32x4 abd[5] = {};
            __builtin_amdgcn_s_setprio(1);
#pragma unroll
            for (int ks = 0; ks < 2; ++ks) {
#pragma unroll
                for (int j = 0; j < 4; ++j) {
                    int rr = j * 16 + lm;
                    s16x8 bk = *reinterpret_cast<const s16x8*>(
                        K_s + rr * 64 + ((4 * ks + kq) ^ (lm & 7)) * 8);
                    aac[j] = __builtin_amdgcn_mfma_f32_16x16x32_bf16(aq[ks], bk, aac[j], 0, 0, 0);
                }
#pragma unroll
                for (int j = 0; j < 5; ++j) {
                    int rr = woff + j * 16 + lm;                 // [0,127]
                    const short* rbuf = r_s[(kt + (rr >> 6)) & 1];  // uniform per j
                    s16x8 br = *reinterpret_cast<const s16x8*>(
                        rbuf + (rr & 63) * 64 + ((4 * ks + kq) ^ (lm & 7)) * 8);
                    abd[j] = __builtin_amdgcn_mfma_f32_16x16x32_bf16(av[ks], br, abd[j], 0, 0, 0);
                }
            }
            __builtin_amdgcn_s_setprio(0);
            // bd -> LDS (bf16), wave-own rows; col c holds u_l = woff + c
#pragma unroll
            for (int j = 0; j < 5; ++j)
#pragma unroll
                for (int r = 0; r < 4; ++r)
                    bd_s[w * 16 + kq * 4 + r][j * 16 + lm] = f2bf(abd[j][r]);

            const bool fullTile = (kt + 1 < n_kt);   // causal mask all-true
            if (pass == 0) {
                if (fullTile) {
#pragma unroll
                    for (int jj = 0; jj < 4; ++jj)
#pragma unroll
                        for (int r = 0; r < 4; ++r) {
                            int q_ls = w * 16 + kq * 4 + r;
                            int c = jj * 16 + lm - kq * 4 - r + 15;
                            float s = (aac[jj][r] + bf2f(bd_s[q_ls][c])) * 0.125f;
                            lsum[r] += __expf(s);
                        }
                } else {
#pragma unroll
                    for (int jj = 0; jj < 4; ++jj)
#pragma unroll
                        for (int r = 0; r < 4; ++r) {
                            int q_ls = w * 16 + kq * 4 + r;
                            int c = jj * 16 + lm - kq * 4 - r + 15;
                            float s = (aac[jj][r] + bf2f(bd_s[q_ls][c])) * 0.125f;
                            bool ok = (k0 + jj * 16 + lm) <= (q0 + q_ls);
                            lsum[r] += ok ? __expf(s) : 0.0f;
                        }
                }
            } else {
                // all gathers before any overlay write (wave-order DS)
                float sv[4][4];
#pragma unroll
                for (int jj = 0; jj < 4; ++jj)
#pragma unroll
                    for (int r = 0; r < 4; ++r) {
                        int c = jj * 16 + lm - kq * 4 - r + 15;
                        sv[jj][r] = (aac[jj][r] + bf2f(bd_s[w * 16 + kq * 4 + r][c])) * 0.125f;
                    }
                short* ew = &bd_s[w * 16][0];   // wave-private overlay, stride 80
                if (fullTile) {
#pragma unroll
                    for (int jj = 0; jj < 4; ++jj)
#pragma unroll
                        for (int r = 0; r < 4; ++r) {
                            int q_ls = w * 16 + kq * 4 + r;
                            int kk = k0 + jj * 16 + lm;
                            float a = __expf(sv[jj][r]) * linv[r];
                            attn[((size_t)bh * NS + q0 + q_ls) * NS + kk] = a;
                            ew[(kq * 4 + r) * 80 + jj * 16 + lm] = f2bf(a);
                        }
                } else {
#pragma unroll
                    for (int jj = 0; jj < 4; ++jj)
#pragma unroll
                        for (int r = 0; r < 4; ++r) {
                            int q_ls = w * 16 + kq * 4 + r;
                            int kk = k0 + jj * 16 + lm;
                            bool ok = kk <= (q0 + q_ls);
                            float a = ok ? __expf(sv[jj][r]) * linv[r] : 0.0f;
                            attn[((size_t)bh * NS + q0 + q_ls) * NS + kk] = a;
                            ew[(kq * 4 + r) * 80 + jj * 16 + lm] = f2bf(a);
                        }
                }
                // PV: A-frags from e overlay, B-frags from V_s (vT rows = n)
#pragma unroll
                for (int ks = 0; ks < 2; ++ks) {
                    s16x8 ae = *reinterpret_cast<const s16x8*>(ew + lm * 80 + ks * 32 + kq * 8);
#pragma unroll
                    for (int jn = 0; jn < 4; ++jn) {
                        s16x8 bv = *reinterpret_cast<const s16x8*>(
                            V_s + (jn * 16 + lm) * 64 + ((4 * ks + kq) ^ (lm & 7)) * 8);
                        apv[jn] = __builtin_amdgcn_mfma_f32_16x16x32_bf16(ae, bv, apv[jn], 0, 0, 0);
                    }
                }
            }
        }
        if (pass == 0) {
#pragma unroll
            for (int r = 0; r < 4; ++r) {
                float v = lsum[r];
                v += __shfl_xor(v, 1); v += __shfl_xor(v, 2);
                v += __shfl_xor(v, 4); v += __shfl_xor(v, 8);
                linv[r] = 1.0f / v;
            }
        }
    }

    // ctx write (bf16)
#pragma unroll
    for (int jn = 0; jn < 4; ++jn)
#pragma unroll
        for (int r = 0; r < 4; ++r)
            ctx[(size_t)(b * NS + q0 + w * 16 + kq * 4 + r) * ND + h * NDH + jn * 16 + lm] =
                f2bf(apv[jn][r]);
}

// ---------------------------------------------------------------------------
// out = LayerNorm(sin) * g + b (residual already folded into sin by the
// producing GEMM's epilogue). Optional bf16 twin output.
// ---------------------------------------------------------------------------
__global__ __launch_bounds__(256) void ln_kernel(
    const float* __restrict__ sin_,
    const float* __restrict__ g, const float* __restrict__ bb,
    float* __restrict__ out, short* __restrict__ out_bf)
{
    __shared__ float red[4];
    __shared__ float red2[4];
    const int row = blockIdx.x;
    const size_t base = (size_t)row * ND;
    const int tid = threadIdx.x;
    const int lane = tid & 63, w = tid >> 6;

    float v0 = sin_[base + tid];
    float v1 = sin_[base + tid + 256];
    float s = v0 + v1;
#pragma unroll
    for (int o = 32; o > 0; o >>= 1) s += __shfl_xor(s, o);
    if (lane == 0) red[w] = s;
    __syncthreads();
    float mu = (red[0] + red[1] + red[2] + red[3]) * (1.0f / ND);
    float d0 = v0 - mu, d1 = v1 - mu;
    float vs = d0 * d0 + d1 * d1;
#pragma unroll
    for (int o = 32; o > 0; o >>= 1) vs += __shfl_xor(vs, o);
    if (lane == 0) red2[w] = vs;
    __syncthreads();
    float var = (red2[0] + red2[1] + red2[2] + red2[3]) * (1.0f / ND);
    float rs = rsqrtf(var + 1e-5f);
    float o0 = d0 * rs * g[tid] + bb[tid];
    float o1 = d1 * rs * g[tid + 256] + bb[tid + 256];
    out[base + tid] = o0;
    out[base + tid + 256] = o1;
    if (out_bf) {
        out_bf[base + tid] = f2bf(o0);
        out_bf[base + tid + 256] = f2bf(o1);
    }
}

// ---------------------------------------------------------------------------
extern "C" void kernel_launch(void* const* d_in, const int* in_sizes, int n_in,
                              void* d_out, int out_size, void* d_ws, size_t ws_size,
                              hipStream_t stream)
{
    const float* x   = (const float*)d_in[0];
    const float* rel = (const float*)d_in[1];
    const float* Wq = (const float*)d_in[3];
    const float* Wk = (const float*)d_in[4];
    const float* Wv = (const float*)d_in[5];
    const float* Wr = (const float*)d_in[6];
    const float* Wo = (const float*)d_in[7];
    const float* ub = (const float*)d_in[8];
    const float* vb = (const float*)d_in[9];
    const float* g1 = (const float*)d_in[10];
    const float* be1 = (const float*)d_in[11];
    const float* W1 = (const float*)d_in[12];
    const float* bb1 = (const float*)d_in[13];
    const float* W2 = (const float*)d_in[14];
    const float* bb2 = (const float*)d_in[15];
    const float* g2 = (const float*)d_in[16];
    const float* be2 = (const float*)d_in[17];

    float* out0 = (float*)d_out;                 // (B,S,D) f32
    float* attn = out0 + (size_t)NB * NS * ND;   // (B,H,S,S) f32

    // workspace layout
    char* ws = (char*)d_ws;
    const size_t SZ_F32 = (size_t)NB * NS * ND * 4;    // 16 MB
    const size_t SZ_BF  = (size_t)NB * NS * ND * 2;    // 8 MB
    const size_t SZ_MID = (size_t)NB * NS * NDF * 2;   // 32 MB
    const size_t SZ_RBF = (size_t)NS * ND * 2;         // 1 MB
    const size_t SZ_W   = (size_t)ND * ND * 2;         // 512 KB
    const size_t SZ_W12 = (size_t)ND * NDF * 2;        // 2 MB
    const size_t needed = 2 * SZ_F32 + 8 * SZ_BF + SZ_MID + 2 * SZ_RBF + 5 * SZ_W + 2 * SZ_W12;
    if (ws_size < needed) return;

    float* tmp  = (float*)ws; ws += SZ_F32;
    float* h1   = (float*)ws; ws += SZ_F32;
    short* x_bf = (short*)ws; ws += SZ_BF;
    short* qu_bf = (short*)ws; ws += SZ_BF;
    short* qv_bf = (short*)ws; ws += SZ_BF;  // unused (layout stability)
    short* k_bf = (short*)ws; ws += SZ_BF;
    short* vbuf = (short*)ws; ws += SZ_BF;   // unused (layout stability)
    short* vT   = (short*)ws; ws += SZ_BF;
    short* ctx  = (short*)ws; ws += SZ_BF;
    short* h1b  = (short*)ws; ws += SZ_BF;
    short* mid  = (short*)ws; ws += SZ_MID;
    short* rel_bf = (short*)ws; ws += SZ_RBF;
    short* r_bf   = (short*)ws; ws += SZ_RBF;
    short* Wqkv = (short*)ws; ws += 3 * SZ_W;    // [1536][512]: Wq^T,Wk^T,Wv^T
    short* WrT = (short*)ws; ws += SZ_W;
    short* WoT = (short*)ws; ws += SZ_W;
    short* W1T = (short*)ws; ws += SZ_W12;       // (NDF, ND)
    short* W2T = (short*)ws; ws += SZ_W12;       // (ND, NDF)
    (void)vbuf; (void)qv_bf;

    dim3 blk(256);
    const int M = NB * NS;

    // merged prep: input casts + all weight transposes in ONE launch
    TP7 tp;
    tp.src[0] = Wq; tp.dst[0] = Wqkv;                 tp.K[0] = ND;  tp.N[0] = ND;
    tp.src[1] = Wk; tp.dst[1] = Wqkv + (size_t)ND * ND;     tp.K[1] = ND;  tp.N[1] = ND;
    tp.src[2] = Wv; tp.dst[2] = Wqkv + (size_t)2 * ND * ND; tp.K[2] = ND;  tp.N[2] = ND;
    tp.src[3] = Wr; tp.dst[3] = WrT;                  tp.K[3] = ND;  tp.N[3] = ND;
    tp.src[4] = Wo; tp.dst[4] = WoT;                  tp.K[4] = ND;  tp.N[4] = ND;
    tp.src[5] = W1; tp.dst[5] = W1T;                  tp.K[5] = ND;  tp.N[5] = NDF;
    tp.src[6] = W2; tp.dst[6] = W2T;                  tp.K[6] = NDF; tp.N[6] = ND;
    prep_kernel<<<dim3(1024, 1, 8), blk, 0, stream>>>(
        tp, (const float4*)x, M * ND / 4, (const float4*)rel, NS * ND / 4, x_bf, rel_bf);

    // QKV + rel projections; V written directly transposed; qv not stored
    qkvr_gemm_kernel<<<dim3(16, M / 128), blk, 0, stream>>>(
        x_bf, Wqkv, rel_bf, WrT, ub, qu_bf, k_bf, vT, r_bf);

    // fused scores + softmax + attn write + PV
    fused_attn_kernel<<<dim3(NB * NH * 16), blk, 0, stream>>>(
        qu_bf, k_bf, r_bf, vT, ub, vb, attn, ctx);

    // output proj with fused residual (+x) -> tmp = x + ctx@Wo, then LN1
    mfma_gemm64_kernel<float><<<dim3(ND / 64, M / 128), blk, 0, stream>>>(
        ctx, WoT, nullptr, x, tmp, M, ND, ND, 0);
    ln_kernel<<<dim3(M), blk, 0, stream>>>(tmp, g1, be1, h1, h1b);

    // FFN: FF1 (bias+relu) -> mid; FF2 with fused residual (+h1) -> tmp; LN2
    mfma_gemm_kernel<bf16><<<dim3(NDF / 128, M / 128), blk, 0, stream>>>(
        h1b, W1T, bb1, (bf16*)mid, M, NDF, ND, 1);
    mfma_gemm64_kernel<float><<<dim3(ND / 64, M / 128), blk, 0, stream>>>(
        mid, W2T, bb2, h1, tmp, M, ND, NDF, 0);
    ln_kernel<<<dim3(M), blk, 0, stream>>>(tmp, g2, be2, out0, nullptr);
}

// Round 22
// 258.982 us; speedup vs baseline: 1.0606x; 1.0606x over previous
//
#include <hip/hip_runtime.h>
#include <hip/hip_bf16.h>

typedef __hip_bfloat16 bf16;

#define NB 8
#define NS 1024
#define ND 512
#define NH 8
#define NDH 64
#define NDF 2048

typedef __attribute__((ext_vector_type(8))) short s16x8;
typedef __attribute__((ext_vector_type(4))) float f32x4;

__device__ __forceinline__ void storev(float* p, float v) { *p = v; }
__device__ __forceinline__ void storev(bf16* p, float v) { *p = __float2bfloat16(v); }
__device__ __forceinline__ short f2bf(float f) {
    bf16 h = __float2bfloat16(f);
    return *reinterpret_cast<short*>(&h);
}
__device__ __forceinline__ float bf2f(short s) {
    bf16 h = *reinterpret_cast<bf16*>(&s);
    return __bfloat162float(h);
}

// direct global->LDS 16B copy (wave-uniform LDS base + lane*16 dest)
__device__ __forceinline__ void gload_lds16(const short* g, short* l) {
    __builtin_amdgcn_global_load_lds(
        (const __attribute__((address_space(1))) unsigned int*)g,
        (__attribute__((address_space(3))) unsigned int*)l, 16, 0, 0);
}

// XCD-aware bijective block swizzle (T1): consecutive logical rows group on
// one XCD so A row-panels stay in its private L2. Requires nwg % 8 == 0.
__device__ __forceinline__ void xcd_swizzle(int& bx, int& by) {
    int gx = gridDim.x;
    int nwg = gx * gridDim.y;
    int flat = by * gx + bx;
    int swz = (flat & 7) * (nwg >> 3) + (flat >> 3);
    bx = swz % gx;
    by = swz / gx;
}

// ---------------------------------------------------------------------------
// Merged prep: z<7 -> weight transposes (W[K][N] f32 -> Wt[N][K] bf16);
// z==7 -> input casts f32->bf16 (grid-stride).
// ---------------------------------------------------------------------------
struct TP7 {
    const float* src[7];
    short* dst[7];
    int K[7];
    int N[7];
};

__global__ __launch_bounds__(256) void prep_kernel(
    TP7 p, const float4* __restrict__ inA, int n4a,
    const float4* __restrict__ inB, int n4b,
    short* __restrict__ outA, short* __restrict__ outB)
{
    __shared__ float t[32][33];
    const int z = blockIdx.z;
    if (z == 7) {
        for (int i = blockIdx.x * 256 + threadIdx.x; i < n4a + n4b; i += 1024 * 256) {
            const float4* s; short* d; int j;
            if (i < n4a) { s = inA; d = outA; j = i; }
            else { s = inB; d = outB; j = i - n4a; }
            float4 v = s[j];
            short4 o;
            o.x = f2bf(v.x); o.y = f2bf(v.y); o.z = f2bf(v.z); o.w = f2bf(v.w);
            *reinterpret_cast<short4*>(d + (size_t)j * 4) = o;
        }
        return;
    }
    const float* src = p.src[z];
    short* dst = p.dst[z];
    const int K = p.K[z], N = p.N[z];
    const int ntx = N >> 5;
    const int f = blockIdx.x;
    if (f >= ntx * (K >> 5)) return;
    const int n0 = (f % ntx) * 32, k0 = (f / ntx) * 32;
    const int tx = threadIdx.x & 31, ty = threadIdx.x >> 5;
#pragma unroll
    for (int i = 0; i < 4; ++i)
        t[ty + i * 8][tx] = src[(size_t)(k0 + ty + i * 8) * N + n0 + tx];
    __syncthreads();
#pragma unroll
    for (int i = 0; i < 4; ++i)
        dst[(size_t)(n0 + ty + i * 8) * K + k0 + tx] = f2bf(t[tx][ty + i * 8]);
}

// ---------------------------------------------------------------------------
// MFMA bf16 GEMM, 128x128 tile, BK=32 double-buffered (R15) + XCD swizzle.
// ---------------------------------------------------------------------------
template <typename CT>
__global__ __launch_bounds__(256) void mfma_gemm_kernel(
    const short* __restrict__ A, const short* __restrict__ Bt,
    const float* __restrict__ bias, CT* __restrict__ C,
    int M, int N, int K, int doRelu)
{
    __shared__ __align__(16) short As[2][128 * 32];
    __shared__ __align__(16) short Bs[2][128 * 32];
    int bx = blockIdx.x, by = blockIdx.y;
    xcd_swizzle(bx, by);
    const int row0 = by * 128;
    const int col0 = bx * 128;
    const int tid = threadIdx.x;
    const int lane = tid & 63, w = tid >> 6;
    const int wm = w >> 1, wn = w & 1;
    const int lm = lane & 15, kq = lane >> 4;
    const int srow = lane >> 2;
    const int schk = lane & 3;

    f32x4 acc[4][4] = {};

    auto stage = [&](int bufi, int k0) {
#pragma unroll
        for (int p = 0; p < 2; ++p) {
            int rbase = p * 64 + w * 16;
            int r = rbase + srow;
            int gc = schk ^ ((r >> 1) & 3);
            gload_lds16(A  + (size_t)(row0 + r) * K + k0 + gc * 8, &As[bufi][rbase * 32]);
            gload_lds16(Bt + (size_t)(col0 + r) * K + k0 + gc * 8, &Bs[bufi][rbase * 32]);
        }
    };

    stage(0, 0);
    __syncthreads();          // tile 0 resident
    int cur = 0;
    for (int k0 = 0; k0 < K; k0 += 32) {
        if (k0 + 32 < K) stage(cur ^ 1, k0 + 32);   // issue next-tile loads
        s16x8 af[4], bfr[4];
#pragma unroll
        for (int i = 0; i < 4; ++i) {
            int ra = wm * 64 + i * 16 + lm;
            int rb = wn * 64 + i * 16 + lm;
            af[i]  = *reinterpret_cast<const s16x8*>(
                &As[cur][ra * 32 + (kq ^ ((ra >> 1) & 3)) * 8]);
            bfr[i] = *reinterpret_cast<const s16x8*>(
                &Bs[cur][rb * 32 + (kq ^ ((rb >> 1) & 3)) * 8]);
        }
#pragma unroll
        for (int i = 0; i < 4; ++i)
#pragma unroll
            for (int j = 0; j < 4; ++j)
                acc[i][j] = __builtin_amdgcn_mfma_f32_16x16x32_bf16(
                    af[i], bfr[j], acc[i][j], 0, 0, 0);
        __syncthreads();      // drains vmcnt: next tile resident
        cur ^= 1;
    }

#pragma unroll
    for (int i = 0; i < 4; ++i) {
        int cr0 = row0 + wm * 64 + i * 16 + kq * 4;
#pragma unroll
        for (int j = 0; j < 4; ++j) {
            int cc = col0 + wn * 64 + j * 16 + lm;
            float bv = bias ? bias[cc] : 0.0f;
#pragma unroll
            for (int r = 0; r < 4; ++r) {
                float v = acc[i][j][r] + bv;
                if (doRelu) v = fmaxf(v, 0.0f);
                storev(&C[(size_t)(cr0 + r) * N + cc], v);
            }
        }
    }
}

// ---------------------------------------------------------------------------
// MFMA bf16 GEMM, 128x64 tile, BK=64, 2-phase double-buffer (R14) + XCD
// swizzle. Grid-limited kernels (Wo/FF2) -> 48 KB LDS is occupancy-free.
// (R21's epilogue-residual fusion REVERTED: resid read after the K-loop in a
// 2-blocks/CU kernel was un-hidden tail latency, measured -14us regression.)
// ---------------------------------------------------------------------------
template <typename CT>
__global__ __launch_bounds__(256) void mfma_gemm64_kernel(
    const short* __restrict__ A, const short* __restrict__ Bt,
    const float* __restrict__ bias, CT* __restrict__ C,
    int M, int N, int K, int doRelu)
{
    __shared__ __align__(16) short As[2][128 * 64];
    __shared__ __align__(16) short Bs[2][64 * 64];
    int bx = blockIdx.x, by = blockIdx.y;
    xcd_swizzle(bx, by);
    const int row0 = by * 128;
    const int col0 = bx * 64;
    const int tid = threadIdx.x;
    const int lane = tid & 63, w = tid >> 6;
    const int wm = w >> 1, wn = w & 1;
    const int lm = lane & 15, kq = lane >> 4;
    const int srow8 = lane >> 3;
    const int schk8 = lane & 7;

    f32x4 acc[4][2] = {};

    auto stage = [&](int bufi, int k0) {
#pragma unroll
        for (int p = 0; p < 4; ++p) {
            int rbase = p * 32 + w * 8;
            int r = rbase + srow8;
            int gc = schk8 ^ (r & 7);
            gload_lds16(A + (size_t)(row0 + r) * K + k0 + gc * 8, &As[bufi][rbase * 64]);
        }
#pragma unroll
        for (int p = 0; p < 2; ++p) {
            int rbase = p * 32 + w * 8;
            int r = rbase + srow8;
            int gc = schk8 ^ (r & 7);
            gload_lds16(Bt + (size_t)(col0 + r) * K + k0 + gc * 8, &Bs[bufi][rbase * 64]);
        }
    };

    stage(0, 0);
    __syncthreads();          // drain: tile 0 resident
    int cur = 0;
    for (int k0 = 0; k0 < K; k0 += 64) {
        if (k0 + 64 < K) stage(cur ^ 1, k0 + 64);   // issue next-tile loads
#pragma unroll
        for (int ks = 0; ks < 2; ++ks) {
            s16x8 af[4], bfr[2];
#pragma unroll
            for (int i = 0; i < 4; ++i) {
                int ra = wm * 64 + i * 16 + lm;
                af[i] = *reinterpret_cast<const s16x8*>(
                    &As[cur][ra * 64 + ((4 * ks + kq) ^ (lm & 7)) * 8]);
            }
#pragma unroll
            for (int j = 0; j < 2; ++j) {
                int rb = wn * 32 + j * 16 + lm;
                bfr[j] = *reinterpret_cast<const s16x8*>(
                    &Bs[cur][rb * 64 + ((4 * ks + kq) ^ (lm & 7)) * 8]);
            }
#pragma unroll
            for (int i = 0; i < 4; ++i)
#pragma unroll
                for (int j = 0; j < 2; ++j)
                    acc[i][j] = __builtin_amdgcn_mfma_f32_16x16x32_bf16(
                        af[i], bfr[j], acc[i][j], 0, 0, 0);
        }
        __syncthreads();      // drains vmcnt: next tile resident; cur consumed
        cur ^= 1;
    }

#pragma unroll
    for (int i = 0; i < 4; ++i) {
        int cr0 = row0 + wm * 64 + i * 16 + kq * 4;
#pragma unroll
        for (int j = 0; j < 2; ++j) {
            int cc = col0 + wn * 32 + j * 16 + lm;
            float bv = bias ? bias[cc] : 0.0f;
#pragma unroll
            for (int r = 0; r < 4; ++r) {
                float v = acc[i][j][r] + bv;
                if (doRelu) v = fmaxf(v, 0.0f);
                storev(&C[(size_t)(cr0 + r) * N + cc], v);
            }
        }
    }
}

// ---------------------------------------------------------------------------
// Fused QKV + rel projection, BK=32 double-buffered (R15) + XCD swizzle.
// V epilogue (sec==2) writes DIRECTLY TRANSPOSED into vT (R18 win).
// qv not materialized (R19 win): fused_attn derives av = aq - ub + vb.
// ---------------------------------------------------------------------------
__global__ __launch_bounds__(256) void qkvr_gemm_kernel(
    const short* __restrict__ x_bf, const short* __restrict__ Wqkv,
    const short* __restrict__ rel_bf, const short* __restrict__ WrT,
    const float* __restrict__ ub,
    short* __restrict__ qu,
    short* __restrict__ kb, short* __restrict__ vT,
    short* __restrict__ r_bf)
{
    int bx = blockIdx.x, by = blockIdx.y;
    xcd_swizzle(bx, by);
    const int isRel = bx >= 12;
    if (isRel && by >= 8) return;
    const short* A  = isRel ? rel_bf : x_bf;
    const short* Bt = isRel ? WrT : Wqkv;
    const int col0 = isRel ? (bx - 12) * 128 : bx * 128;
    const int row0 = by * 128;

    __shared__ __align__(16) short As[2][128 * 32];
    __shared__ __align__(16) short Bs[2][128 * 32];
    const int tid = threadIdx.x;
    const int lane = tid & 63, w = tid >> 6;
    const int wm = w >> 1, wn = w & 1;
    const int lm = lane & 15, kq = lane >> 4;
    const int srow = lane >> 2;
    const int schk = lane & 3;

    f32x4 acc[4][4] = {};

    auto stage = [&](int bufi, int k0) {
#pragma unroll
        for (int p = 0; p < 2; ++p) {
            int rbase = p * 64 + w * 16;
            int r = rbase + srow;
            int gc = schk ^ ((r >> 1) & 3);
            gload_lds16(A  + (size_t)(row0 + r) * ND + k0 + gc * 8, &As[bufi][rbase * 32]);
            gload_lds16(Bt + (size_t)(col0 + r) * ND + k0 + gc * 8, &Bs[bufi][rbase * 32]);
        }
    };

    stage(0, 0);
    __syncthreads();
    int cur = 0;
    for (int k0 = 0; k0 < ND; k0 += 32) {
        if (k0 + 32 < ND) stage(cur ^ 1, k0 + 32);
        s16x8 af[4], bfr[4];
#pragma unroll
        for (int i = 0; i < 4; ++i) {
            int ra = wm * 64 + i * 16 + lm;
            int rb = wn * 64 + i * 16 + lm;
            af[i]  = *reinterpret_cast<const s16x8*>(
                &As[cur][ra * 32 + (kq ^ ((ra >> 1) & 3)) * 8]);
            bfr[i] = *reinterpret_cast<const s16x8*>(
                &Bs[cur][rb * 32 + (kq ^ ((rb >> 1) & 3)) * 8]);
        }
#pragma unroll
        for (int i = 0; i < 4; ++i)
#pragma unroll
            for (int j = 0; j < 4; ++j)
                acc[i][j] = __builtin_amdgcn_mfma_f32_16x16x32_bf16(
                    af[i], bfr[j], acc[i][j], 0, 0, 0);
        __syncthreads();
        cur ^= 1;
    }

    const int sec = col0 >> 9;  // uniform per block (qkv path)
#pragma unroll
    for (int i = 0; i < 4; ++i) {
        int cr0 = row0 + wm * 64 + i * 16 + kq * 4;
#pragma unroll
        for (int j = 0; j < 4; ++j) {
            int cc = col0 + wn * 64 + j * 16 + lm;
            int c5 = cc & 511;
            if (!isRel && sec == 2) {
                // V: direct transposed store (4 consecutive s at fixed h,n)
                int hh = c5 >> 6, nn = c5 & 63;
                int bb_ = row0 >> 10;                 // block spans one b
                int s = cr0 - (bb_ << 10);
                short4 o;
                o.x = f2bf(acc[i][j][0]); o.y = f2bf(acc[i][j][1]);
                o.z = f2bf(acc[i][j][2]); o.w = f2bf(acc[i][j][3]);
                *reinterpret_cast<short4*>(
                    vT + (((size_t)(bb_ * NH + hh) * NDH + nn) * NS + s)) = o;
            } else {
#pragma unroll
                for (int r = 0; r < 4; ++r) {
                    float a = acc[i][j][r];
                    size_t idx = (size_t)(cr0 + r) * ND + c5;
                    if (isRel) {
                        r_bf[idx] = f2bf(a);
                    } else if (sec == 0) {
                        qu[idx] = f2bf(a + ub[c5]);
                    } else {
                        kb[idx] = f2bf(a);
                    }
                }
            }
        }
    }
}

// ---------------------------------------------------------------------------
// Fused attention — R7 structure (frozen) + av derived in-register (R19) +
// hoisted zero-fill and full-tile fast path (R20, measured win).
// ---------------------------------------------------------------------------
__global__ __launch_bounds__(256) void fused_attn_kernel(
    const short* __restrict__ qu,
    const short* __restrict__ kb, const short* __restrict__ rb,
    const short* __restrict__ vT,
    const float* __restrict__ ub, const float* __restrict__ vb,
    float* __restrict__ attn, short* __restrict__ ctx)
{
    __shared__ __align__(16) short K_s[64 * 64];
    __shared__ __align__(16) short V_s[64 * 64];
    __shared__ __align__(16) short r_s[2][64 * 64];
    __shared__ __align__(16) short bd_s[64][80];  // bd gather tile / e overlay

    const int bid = blockIdx.x;
    const int strip = 15 - (bid >> 6);      // heavy strips first
    const int bh = bid & 63;
    const int h = bh & (NH - 1), b = bh >> 3;
    const int q0 = strip * 64;
    const int n_kt = strip + 1;
    const int tid = threadIdx.x;
    const int lane = tid & 63, w = tid >> 6;
    const int lm = lane & 15, kq = lane >> 4;
    const int woff = 48 - w * 16;           // per-wave u-window base
    const int srow8 = lane >> 3;            // staging: row within 8-row group
    const int schk8 = lane & 7;             // staging: 16B chunk within 64-short row

    // loop-invariant A-fragments; av derived from aq via bias delta
    s16x8 aq[2], av[2];
#pragma unroll
    for (int ks = 0; ks < 2; ++ks) {
        const size_t off = (size_t)(b * NS + q0 + w * 16 + lm) * ND + h * NDH + ks * 32 + kq * 8;
        aq[ks] = *reinterpret_cast<const s16x8*>(qu + off);
        const int dbase = h * NDH + ks * 32 + kq * 8;
#pragma unroll
        for (int e = 0; e < 8; ++e) {
            float t = bf2f(aq[ks][e]) - ub[dbase + e] + vb[dbase + e];
            av[ks][e] = f2bf(t);
        }
    }

    // zero-fill k >= n_kt*64 FIRST: pure stores overlap first-tile latency;
    // region disjoint from everything the passes write.
    {
        const int z = NS - n_kt * 64;
        if (z > 0) {
            const int z4 = z >> 2;
            float4 zz = make_float4(0.f, 0.f, 0.f, 0.f);
            for (int i = tid; i < 64 * z4; i += 256) {
                int zr = i / z4, zc = i - zr * z4;
                *reinterpret_cast<float4*>(
                    attn + ((size_t)bh * NS + q0 + zr) * NS + n_kt * 64 + zc * 4) = zz;
            }
        }
    }

    f32x4 apv[4] = {};
    float linv[4];

    for (int pass = 0; pass < 2; ++pass) {
        float lsum[4] = {0.f, 0.f, 0.f, 0.f};
        for (int kt = 0; kt < n_kt; ++kt) {
            const int k0 = kt * 64;
            const int ub0 = k0 - q0 + 960;   // u-window base (>= 0)
            __syncthreads();                 // prev tile fully consumed
            // K tile: 64 rows x 64 shorts, linear, swizzled source chunk
#pragma unroll
            for (int p = 0; p < 2; ++p) {
                int rbase = p * 32 + w * 8;
                int grow = rbase + srow8;
                int gc = schk8 ^ (grow & 7);
                gload_lds16(kb + (size_t)(b * NS + k0 + grow) * ND + h * NDH + gc * 8,
                            K_s + rbase * 64);
            }
            if (pass) {
#pragma unroll
                for (int p = 0; p < 2; ++p) {
                    int rbase = p * 32 + w * 8;
                    int grow = rbase + srow8;
                    int gc = schk8 ^ (grow & 7);
                    gload_lds16(vT + ((size_t)bh * NDH + grow) * NS + k0 + gc * 8,
                                V_s + rbase * 64);
                }
            }
            // r ping-pong: L_kt in r_s[kt&1], U_kt in r_s[(kt+1)&1]
            if (kt == 0) {
#pragma unroll
                for (int half = 0; half < 2; ++half)
#pragma unroll
                    for (int p = 0; p < 2; ++p) {
                        int rbase = p * 32 + w * 8;
                        int grow = rbase + srow8;
                        int ur = ub0 + half * 64 + grow; ur = ur > 1023 ? 1023 : ur;
                        int gc = schk8 ^ (grow & 7);
                        gload_lds16(rb + (size_t)ur * ND + h * NDH + gc * 8,
                                    r_s[half] + rbase * 64);
                    }
            } else {
#pragma unroll
                for (int p = 0; p < 2; ++p) {
                    int rbase = p * 32 + w * 8;
                    int grow = rbase + srow8;
                    int ur = ub0 + 64 + grow; ur = ur > 1023 ? 1023 : ur;
                    int gc = schk8 ^ (grow & 7);
                    gload_lds16(rb + (size_t)ur * ND + h * NDH + gc * 8,
                                r_s[(kt + 1) & 1] + rbase * 64);
                }
            }
            __syncthreads();

            f32x4 aac[4] = {};
            f32x4 abd[5] = {};
            __builtin_amdgcn_s_setprio(1);
#pragma unroll
            for (int ks = 0; ks < 2; ++ks) {
#pragma unroll
                for (int j = 0; j < 4; ++j) {
                    int rr = j * 16 + lm;
                    s16x8 bk = *reinterpret_cast<const s16x8*>(
                        K_s + rr * 64 + ((4 * ks + kq) ^ (lm & 7)) * 8);
                    aac[j] = __builtin_amdgcn_mfma_f32_16x16x32_bf16(aq[ks], bk, aac[j], 0, 0, 0);
                }
#pragma unroll
                for (int j = 0; j < 5; ++j) {
                    int rr = woff + j * 16 + lm;                 // [0,127]
                    const short* rbuf = r_s[(kt + (rr >> 6)) & 1];  // uniform per j
                    s16x8 br = *reinterpret_cast<const s16x8*>(
                        rbuf + (rr & 63) * 64 + ((4 * ks + kq) ^ (lm & 7)) * 8);
                    abd[j] = __builtin_amdgcn_mfma_f32_16x16x32_bf16(av[ks], br, abd[j], 0, 0, 0);
                }
            }
            __builtin_amdgcn_s_setprio(0);
            // bd -> LDS (bf16), wave-own rows; col c holds u_l = woff + c
#pragma unroll
            for (int j = 0; j < 5; ++j)
#pragma unroll
                for (int r = 0; r < 4; ++r)
                    bd_s[w * 16 + kq * 4 + r][j * 16 + lm] = f2bf(abd[j][r]);

            const bool fullTile = (kt + 1 < n_kt);   // causal mask all-true
            if (pass == 0) {
                if (fullTile) {
#pragma unroll
                    for (int jj = 0; jj < 4; ++jj)
#pragma unroll
                        for (int r = 0; r < 4; ++r) {
                            int q_ls = w * 16 + kq * 4 + r;
                            int c = jj * 16 + lm - kq * 4 - r + 15;
                            float s = (aac[jj][r] + bf2f(bd_s[q_ls][c])) * 0.125f;
                            lsum[r] += __expf(s);
                        }
                } else {
#pragma unroll
                    for (int jj = 0; jj < 4; ++jj)
#pragma unroll
                        for (int r = 0; r < 4; ++r) {
                            int q_ls = w * 16 + kq * 4 + r;
                            int c = jj * 16 + lm - kq * 4 - r + 15;
                            float s = (aac[jj][r] + bf2f(bd_s[q_ls][c])) * 0.125f;
                            bool ok = (k0 + jj * 16 + lm) <= (q0 + q_ls);
                            lsum[r] += ok ? __expf(s) : 0.0f;
                        }
                }
            } else {
                // all gathers before any overlay write (wave-order DS)
                float sv[4][4];
#pragma unroll
                for (int jj = 0; jj < 4; ++jj)
#pragma unroll
                    for (int r = 0; r < 4; ++r) {
                        int c = jj * 16 + lm - kq * 4 - r + 15;
                        sv[jj][r] = (aac[jj][r] + bf2f(bd_s[w * 16 + kq * 4 + r][c])) * 0.125f;
                    }
                short* ew = &bd_s[w * 16][0];   // wave-private overlay, stride 80
                if (fullTile) {
#pragma unroll
                    for (int jj = 0; jj < 4; ++jj)
#pragma unroll
                        for (int r = 0; r < 4; ++r) {
                            int q_ls = w * 16 + kq * 4 + r;
                            int kk = k0 + jj * 16 + lm;
                            float a = __expf(sv[jj][r]) * linv[r];
                            attn[((size_t)bh * NS + q0 + q_ls) * NS + kk] = a;
                            ew[(kq * 4 + r) * 80 + jj * 16 + lm] = f2bf(a);
                        }
                } else {
#pragma unroll
                    for (int jj = 0; jj < 4; ++jj)
#pragma unroll
                        for (int r = 0; r < 4; ++r) {
                            int q_ls = w * 16 + kq * 4 + r;
                            int kk = k0 + jj * 16 + lm;
                            bool ok = kk <= (q0 + q_ls);
                            float a = ok ? __expf(sv[jj][r]) * linv[r] : 0.0f;
                            attn[((size_t)bh * NS + q0 + q_ls) * NS + kk] = a;
                            ew[(kq * 4 + r) * 80 + jj * 16 + lm] = f2bf(a);
                        }
                }
                // PV: A-frags from e overlay, B-frags from V_s (vT rows = n)
#pragma unroll
                for (int ks = 0; ks < 2; ++ks) {
                    s16x8 ae = *reinterpret_cast<const s16x8*>(ew + lm * 80 + ks * 32 + kq * 8);
#pragma unroll
                    for (int jn = 0; jn < 4; ++jn) {
                        s16x8 bv = *reinterpret_cast<const s16x8*>(
                            V_s + (jn * 16 + lm) * 64 + ((4 * ks + kq) ^ (lm & 7)) * 8);
                        apv[jn] = __builtin_amdgcn_mfma_f32_16x16x32_bf16(ae, bv, apv[jn], 0, 0, 0);
                    }
                }
            }
        }
        if (pass == 0) {
#pragma unroll
            for (int r = 0; r < 4; ++r) {
                float v = lsum[r];
                v += __shfl_xor(v, 1); v += __shfl_xor(v, 2);
                v += __shfl_xor(v, 4); v += __shfl_xor(v, 8);
                linv[r] = 1.0f / v;
            }
        }
    }

    // ctx write (bf16)
#pragma unroll
    for (int jn = 0; jn < 4; ++jn)
#pragma unroll
        for (int r = 0; r < 4; ++r)
            ctx[(size_t)(b * NS + q0 + w * 16 + kq * 4 + r) * ND + h * NDH + jn * 16 + lm] =
                f2bf(apv[jn][r]);
}

// ---------------------------------------------------------------------------
// out = LayerNorm(xin + yin) * g + b.  Optional bf16 twin output.
// ---------------------------------------------------------------------------
__global__ __launch_bounds__(256) void add_ln_kernel(
    const float* __restrict__ xin, const float* __restrict__ yin,
    const float* __restrict__ g, const float* __restrict__ bb,
    float* __restrict__ out, short* __restrict__ out_bf)
{
    __shared__ float red[4];
    __shared__ float red2[4];
    const int row = blockIdx.x;
    const size_t base = (size_t)row * ND;
    const int tid = threadIdx.x;
    const int lane = tid & 63, w = tid >> 6;

    float v0 = xin[base + tid] + yin[base + tid];
    float v1 = xin[base + tid + 256] + yin[base + tid + 256];
    float s = v0 + v1;
#pragma unroll
    for (int o = 32; o > 0; o >>= 1) s += __shfl_xor(s, o);
    if (lane == 0) red[w] = s;
    __syncthreads();
    float mu = (red[0] + red[1] + red[2] + red[3]) * (1.0f / ND);
    float d0 = v0 - mu, d1 = v1 - mu;
    float vs = d0 * d0 + d1 * d1;
#pragma unroll
    for (int o = 32; o > 0; o >>= 1) vs += __shfl_xor(vs, o);
    if (lane == 0) red2[w] = vs;
    __syncthreads();
    float var = (red2[0] + red2[1] + red2[2] + red2[3]) * (1.0f / ND);
    float rs = rsqrtf(var + 1e-5f);
    float o0 = d0 * rs * g[tid] + bb[tid];
    float o1 = d1 * rs * g[tid + 256] + bb[tid + 256];
    out[base + tid] = o0;
    out[base + tid + 256] = o1;
    if (out_bf) {
        out_bf[base + tid] = f2bf(o0);
        out_bf[base + tid + 256] = f2bf(o1);
    }
}

// ---------------------------------------------------------------------------
extern "C" void kernel_launch(void* const* d_in, const int* in_sizes, int n_in,
                              void* d_out, int out_size, void* d_ws, size_t ws_size,
                              hipStream_t stream)
{
    const float* x   = (const float*)d_in[0];
    const float* rel = (const float*)d_in[1];
    const float* Wq = (const float*)d_in[3];
    const float* Wk = (const float*)d_in[4];
    const float* Wv = (const float*)d_in[5];
    const float* Wr = (const float*)d_in[6];
    const float* Wo = (const float*)d_in[7];
    const float* ub = (const float*)d_in[8];
    const float* vb = (const float*)d_in[9];
    const float* g1 = (const float*)d_in[10];
    const float* be1 = (const float*)d_in[11];
    const float* W1 = (const float*)d_in[12];
    const float* bb1 = (const float*)d_in[13];
    const float* W2 = (const float*)d_in[14];
    const float* bb2 = (const float*)d_in[15];
    const float* g2 = (const float*)d_in[16];
    const float* be2 = (const float*)d_in[17];

    float* out0 = (float*)d_out;                 // (B,S,D) f32
    float* attn = out0 + (size_t)NB * NS * ND;   // (B,H,S,S) f32

    // workspace layout
    char* ws = (char*)d_ws;
    const size_t SZ_F32 = (size_t)NB * NS * ND * 4;    // 16 MB
    const size_t SZ_BF  = (size_t)NB * NS * ND * 2;    // 8 MB
    const size_t SZ_MID = (size_t)NB * NS * NDF * 2;   // 32 MB
    const size_t SZ_RBF = (size_t)NS * ND * 2;         // 1 MB
    const size_t SZ_W   = (size_t)ND * ND * 2;         // 512 KB
    const size_t SZ_W12 = (size_t)ND * NDF * 2;        // 2 MB
    const size_t needed = 2 * SZ_F32 + 8 * SZ_BF + SZ_MID + 2 * SZ_RBF + 5 * SZ_W + 2 * SZ_W12;
    if (ws_size < needed) return;

    float* tmp  = (float*)ws; ws += SZ_F32;
    float* h1   = (float*)ws; ws += SZ_F32;
    short* x_bf = (short*)ws; ws += SZ_BF;
    short* qu_bf = (short*)ws; ws += SZ_BF;
    short* qv_bf = (short*)ws; ws += SZ_BF;  // unused (layout stability)
    short* k_bf = (short*)ws; ws += SZ_BF;
    short* vbuf = (short*)ws; ws += SZ_BF;   // unused (layout stability)
    short* vT   = (short*)ws; ws += SZ_BF;
    short* ctx  = (short*)ws; ws += SZ_BF;
    short* h1b  = (short*)ws; ws += SZ_BF;
    short* mid  = (short*)ws; ws += SZ_MID;
    short* rel_bf = (short*)ws; ws += SZ_RBF;
    short* r_bf   = (short*)ws; ws += SZ_RBF;
    short* Wqkv = (short*)ws; ws += 3 * SZ_W;    // [1536][512]: Wq^T,Wk^T,Wv^T
    short* WrT = (short*)ws; ws += SZ_W;
    short* WoT = (short*)ws; ws += SZ_W;
    short* W1T = (short*)ws; ws += SZ_W12;       // (NDF, ND)
    short* W2T = (short*)ws; ws += SZ_W12;       // (ND, NDF)
    (void)vbuf; (void)qv_bf;

    dim3 blk(256);
    const int M = NB * NS;

    // merged prep: input casts + all weight transposes in ONE launch
    TP7 tp;
    tp.src[0] = Wq; tp.dst[0] = Wqkv;                 tp.K[0] = ND;  tp.N[0] = ND;
    tp.src[1] = Wk; tp.dst[1] = Wqkv + (size_t)ND * ND;     tp.K[1] = ND;  tp.N[1] = ND;
    tp.src[2] = Wv; tp.dst[2] = Wqkv + (size_t)2 * ND * ND; tp.K[2] = ND;  tp.N[2] = ND;
    tp.src[3] = Wr; tp.dst[3] = WrT;                  tp.K[3] = ND;  tp.N[3] = ND;
    tp.src[4] = Wo; tp.dst[4] = WoT;                  tp.K[4] = ND;  tp.N[4] = ND;
    tp.src[5] = W1; tp.dst[5] = W1T;                  tp.K[5] = ND;  tp.N[5] = NDF;
    tp.src[6] = W2; tp.dst[6] = W2T;                  tp.K[6] = NDF; tp.N[6] = ND;
    prep_kernel<<<dim3(1024, 1, 8), blk, 0, stream>>>(
        tp, (const float4*)x, M * ND / 4, (const float4*)rel, NS * ND / 4, x_bf, rel_bf);

    // QKV + rel projections; V written directly transposed; qv not stored
    qkvr_gemm_kernel<<<dim3(16, M / 128), blk, 0, stream>>>(
        x_bf, Wqkv, rel_bf, WrT, ub, qu_bf, k_bf, vT, r_bf);

    // fused scores + softmax + attn write + PV
    fused_attn_kernel<<<dim3(NB * NH * 16), blk, 0, stream>>>(
        qu_bf, k_bf, r_bf, vT, ub, vb, attn, ctx);

    // output proj + LN1 (h1 f32 + bf16 twin)
    mfma_gemm64_kernel<float><<<dim3(ND / 64, M / 128), blk, 0, stream>>>(
        ctx, WoT, nullptr, tmp, M, ND, ND, 0);
    add_ln_kernel<<<dim3(M), blk, 0, stream>>>(x, tmp, g1, be1, h1, h1b);

    // FFN (MFMA) + LN2
    mfma_gemm_kernel<bf16><<<dim3(NDF / 128, M / 128), blk, 0, stream>>>(
        h1b, W1T, bb1, (bf16*)mid, M, NDF, ND, 1);
    mfma_gemm64_kernel<float><<<dim3(ND / 64, M / 128), blk, 0, stream>>>(
        mid, W2T, bb2, tmp, M, ND, NDF, 0);
    add_ln_kernel<<<dim3(M), blk, 0, stream>>>(h1, tmp, g2, be2, out0, nullptr);
}